// Round 17
// baseline (36.070 us; speedup 1.0000x reference)
//
#include <hip/hip_runtime.h>

#define CIN 64
#define COUT 96
#define HW_  1024
#define NTHR 512
#define NITER 5
#define NMF_EPS 1e-20f

// Round-17: DS-instruction-count model (m134: ~12cyc/b128, ~5.8/b32 issue cost).
// Wave-specialized: waves 0-3 stage-1 (8 FMA per b128 via i-pair x [px][j]
// layout, j-half shfl-combine), waves 4-7 stage-2 (16 FMA per 2xb128,
// i-half shfl-combine, in-wave butterfly normalize, h in registers).
// 2 barriers/iter. Register rule: stage-1 live ~116 (wreg96+acc8+flight).
__global__ __launch_bounds__(NTHR) void nmf_kernel(
    const float* __restrict__ x,
    const float* __restrict__ w,
    const float* __restrict__ h0,
    float* __restrict__ out)
{
    __shared__ float Wr[CIN][104];   // [i][j] pad104; stage-2 b128 [i][jq*4]
    __shared__ float Hst[16][100];   // [px][j] pad100; stage-1 b128 [px][j4]
    __shared__ float Tsp[CIN][20];   // [i][px]
    __shared__ float Xs[CIN][20];    // [i][px]

    const int t = threadIdx.x;
    const int wid = t >> 6;
    const int tile = blockIdx.x;
    const int b = tile >> 6;
    const int hw0 = (tile & 63) << 4;

    // ---- staging: Wr (padded rows) ----
    for (int q = t; q < (CIN * COUT) / 4; q += NTHR) {
        const int i = q / 24;
        const int jq = q - i * 24;
        *(float4*)&Wr[i][jq * 4] = ((const float4*)w)[q];
    }

    // ---- stage-1 identity (waves 0-3): (i-pair, j-half, px-quad=wid) ----
    const int ip  = t & 31;
    const int i0  = ip * 2, i1 = i0 + 1;
    const int jh  = (t >> 5) & 1;
    const int jbase = jh * 48;
    const int pq4s1 = wid * 4;                  // valid for wid<4
    // ---- stage-2 identity (waves 4-7): (j-quad, i-half, px-quad=wid-4) ----
    const int l    = t & 63;
    const int jq   = l & 31;
    const bool act2 = (jq < 24);
    const int jq4  = (act2 ? jq : 23) * 4;
    const int ihalf = l >> 5;
    const int ibase = ihalf * 32;
    const int pq4s2 = (wid - 4) * 4;

    float wreg[96];                              // stage-1 threads only (branch-local)
    float4 hj0, hj1, hj2, hj3;                   // stage-2 h registers [4j][4px]

    if (wid < 4) {
        #pragma unroll
        for (int e = 0; e < 12; ++e) {
            const float4 v = *(const float4*)&w[i0 * COUT + jbase + e * 4];
            wreg[e*4+0] = v.x; wreg[e*4+1] = v.y; wreg[e*4+2] = v.z; wreg[e*4+3] = v.w;
        }
        #pragma unroll
        for (int e = 0; e < 12; ++e) {
            const float4 v = *(const float4*)&w[i1 * COUT + jbase + e * 4];
            wreg[48+e*4+0] = v.x; wreg[48+e*4+1] = v.y; wreg[48+e*4+2] = v.z; wreg[48+e*4+3] = v.w;
        }
        if (jh == 0) {                           // Xs init (x per [i][px])
            const size_t xb = ((size_t)b * CIN) * HW_ + hw0 + pq4s1;
            const float4 x0 = *(const float4*)&x[xb + (size_t)i0 * HW_];
            const float4 x1 = *(const float4*)&x[xb + (size_t)i1 * HW_];
            *(float4*)&Xs[i0][pq4s1] = x0;
            *(float4*)&Xs[i1][pq4s1] = x1;
        }
    } else {
        const float4 h4 = *(const float4*)&h0[jq4];
        hj0 = make_float4(h4.x, h4.x, h4.x, h4.x);
        hj1 = make_float4(h4.y, h4.y, h4.y, h4.y);
        hj2 = make_float4(h4.z, h4.z, h4.z, h4.z);
        hj3 = make_float4(h4.w, h4.w, h4.w, h4.w);
        if (act2 && ihalf == 0) {                // Hst init: [px][4j] = h4
            *(float4*)&Hst[pq4s2 + 0][jq4] = h4;
            *(float4*)&Hst[pq4s2 + 1][jq4] = h4;
            *(float4*)&Hst[pq4s2 + 2][jq4] = h4;
            *(float4*)&Hst[pq4s2 + 3][jq4] = h4;
        }
    }
    __syncthreads();

    #pragma unroll 1
    for (int it = 0; it < NITER; ++it) {
        if (wid < 4) {
            // ---- stage 1: denom[px][2i] partials over j-half ----
            float2 a0 = {0,0}, a1 = {0,0}, a2 = {0,0}, a3 = {0,0};
            #pragma unroll
            for (int k = 0; k < 12; ++k) {
                const int jj = k * 4;
                const float4 hv0 = *(const float4*)&Hst[pq4s1 + 0][jbase + jj];
                const float4 hv1 = *(const float4*)&Hst[pq4s1 + 1][jbase + jj];
                const float4 hv2 = *(const float4*)&Hst[pq4s1 + 2][jbase + jj];
                const float4 hv3 = *(const float4*)&Hst[pq4s1 + 3][jbase + jj];
                const float w0 = wreg[jj], w1 = wreg[jj+1], w2 = wreg[jj+2], w3 = wreg[jj+3];
                const float v0 = wreg[48+jj], v1 = wreg[48+jj+1], v2 = wreg[48+jj+2], v3 = wreg[48+jj+3];
                a0.x += hv0.x*w0 + hv0.y*w1 + hv0.z*w2 + hv0.w*w3;
                a0.y += hv0.x*v0 + hv0.y*v1 + hv0.z*v2 + hv0.w*v3;
                a1.x += hv1.x*w0 + hv1.y*w1 + hv1.z*w2 + hv1.w*w3;
                a1.y += hv1.x*v0 + hv1.y*v1 + hv1.z*v2 + hv1.w*v3;
                a2.x += hv2.x*w0 + hv2.y*w1 + hv2.z*w2 + hv2.w*w3;
                a2.y += hv2.x*v0 + hv2.y*v1 + hv2.z*v2 + hv2.w*v3;
                a3.x += hv3.x*w0 + hv3.y*w1 + hv3.z*w2 + hv3.w*w3;
                a3.y += hv3.x*v0 + hv3.y*v1 + hv3.z*v2 + hv3.w*v3;
            }
            // combine j-halves in-wave (jh = lane bit5)
            a0.x += __shfl_xor(a0.x, 32, 64);  a0.y += __shfl_xor(a0.y, 32, 64);
            a1.x += __shfl_xor(a1.x, 32, 64);  a1.y += __shfl_xor(a1.y, 32, 64);
            a2.x += __shfl_xor(a2.x, 32, 64);  a2.y += __shfl_xor(a2.y, 32, 64);
            a3.x += __shfl_xor(a3.x, 32, 64);  a3.y += __shfl_xor(a3.y, 32, 64);
            if (jh == 0) {
                const float4 x0 = *(const float4*)&Xs[i0][pq4s1];
                const float4 x1 = *(const float4*)&Xs[i1][pq4s1];
                float4 t0, t1;
                t0.x = x0.x / (a0.x + NMF_EPS);  t1.x = x1.x / (a0.y + NMF_EPS);
                t0.y = x0.y / (a1.x + NMF_EPS);  t1.y = x1.y / (a1.y + NMF_EPS);
                t0.z = x0.z / (a2.x + NMF_EPS);  t1.z = x1.z / (a2.y + NMF_EPS);
                t0.w = x0.w / (a3.x + NMF_EPS);  t1.w = x1.w / (a3.y + NMF_EPS);
                *(float4*)&Tsp[i0][pq4s1] = t0;
                *(float4*)&Tsp[i1][pq4s1] = t1;
            }
        }
        __syncthreads();   // barrier A: Tsp ready

        if (wid >= 4) {
            // ---- stage 2: u[4j][4px] over i-half ----
            float4 u0 = {0,0,0,0}, u1 = {0,0,0,0}, u2 = {0,0,0,0}, u3 = {0,0,0,0};
            #pragma unroll
            for (int ii = 0; ii < 32; ++ii) {
                const int i = ibase + ii;
                const float4 wv4 = *(const float4*)&Wr[i][jq4];
                const float4 tv  = *(const float4*)&Tsp[i][pq4s2];
                u0.x += wv4.x*tv.x; u0.y += wv4.x*tv.y; u0.z += wv4.x*tv.z; u0.w += wv4.x*tv.w;
                u1.x += wv4.y*tv.x; u1.y += wv4.y*tv.y; u1.z += wv4.y*tv.z; u1.w += wv4.y*tv.w;
                u2.x += wv4.z*tv.x; u2.y += wv4.z*tv.y; u2.z += wv4.z*tv.z; u2.w += wv4.z*tv.w;
                u3.x += wv4.w*tv.x; u3.y += wv4.w*tv.y; u3.z += wv4.w*tv.z; u3.w += wv4.w*tv.w;
            }
            // combine i-halves in-wave (ihalf = lane bit5)
            u0.x += __shfl_xor(u0.x, 32, 64); u0.y += __shfl_xor(u0.y, 32, 64);
            u0.z += __shfl_xor(u0.z, 32, 64); u0.w += __shfl_xor(u0.w, 32, 64);
            u1.x += __shfl_xor(u1.x, 32, 64); u1.y += __shfl_xor(u1.y, 32, 64);
            u1.z += __shfl_xor(u1.z, 32, 64); u1.w += __shfl_xor(u1.w, 32, 64);
            u2.x += __shfl_xor(u2.x, 32, 64); u2.y += __shfl_xor(u2.y, 32, 64);
            u2.z += __shfl_xor(u2.z, 32, 64); u2.w += __shfl_xor(u2.w, 32, 64);
            u3.x += __shfl_xor(u3.x, 32, 64); u3.y += __shfl_xor(u3.y, 32, 64);
            u3.z += __shfl_xor(u3.z, 32, 64); u3.w += __shfl_xor(u3.w, 32, 64);
            // h' = h*(1+u)
            float4 p0, p1, p2, p3;
            p0.x = hj0.x*(1.f+u0.x); p0.y = hj0.y*(1.f+u0.y); p0.z = hj0.z*(1.f+u0.z); p0.w = hj0.w*(1.f+u0.w);
            p1.x = hj1.x*(1.f+u1.x); p1.y = hj1.y*(1.f+u1.y); p1.z = hj1.z*(1.f+u1.z); p1.w = hj1.w*(1.f+u1.w);
            p2.x = hj2.x*(1.f+u2.x); p2.y = hj2.y*(1.f+u2.y); p2.z = hj2.z*(1.f+u2.z); p2.w = hj2.w*(1.f+u2.w);
            p3.x = hj3.x*(1.f+u3.x); p3.y = hj3.y*(1.f+u3.y); p3.z = hj3.z*(1.f+u3.z); p3.w = hj3.w*(1.f+u3.w);
            // per-px j-sum; idle j-quads contribute zero; butterfly over 24 jq lanes
            float4 s;
            s.x = (p0.x + p1.x) + (p2.x + p3.x);
            s.y = (p0.y + p1.y) + (p2.y + p3.y);
            s.z = (p0.z + p1.z) + (p2.z + p3.z);
            s.w = (p0.w + p1.w) + (p2.w + p3.w);
            if (!act2) { s.x = 0.f; s.y = 0.f; s.z = 0.f; s.w = 0.f; }
            #pragma unroll
            for (int d = 16; d >= 1; d >>= 1) {
                s.x += __shfl_xor(s.x, d, 64);
                s.y += __shfl_xor(s.y, d, 64);
                s.z += __shfl_xor(s.z, d, 64);
                s.w += __shfl_xor(s.w, d, 64);
            }
            const float i0v = 1.f / (s.x + NMF_EPS), i1v = 1.f / (s.y + NMF_EPS);
            const float i2v = 1.f / (s.z + NMF_EPS), i3v = 1.f / (s.w + NMF_EPS);
            hj0.x = p0.x*i0v; hj0.y = p0.y*i1v; hj0.z = p0.z*i2v; hj0.w = p0.w*i3v;
            hj1.x = p1.x*i0v; hj1.y = p1.y*i1v; hj1.z = p1.z*i2v; hj1.w = p1.w*i3v;
            hj2.x = p2.x*i0v; hj2.y = p2.y*i1v; hj2.z = p2.z*i2v; hj2.w = p2.w*i3v;
            hj3.x = p3.x*i0v; hj3.y = p3.y*i1v; hj3.z = p3.z*i2v; hj3.w = p3.w*i3v;
            if (act2 && ihalf == 0) {            // transposed write: [px][4j]
                *(float4*)&Hst[pq4s2 + 0][jq4] = make_float4(hj0.x, hj1.x, hj2.x, hj3.x);
                *(float4*)&Hst[pq4s2 + 1][jq4] = make_float4(hj0.y, hj1.y, hj2.y, hj3.y);
                *(float4*)&Hst[pq4s2 + 2][jq4] = make_float4(hj0.z, hj1.z, hj2.z, hj3.z);
                *(float4*)&Hst[pq4s2 + 3][jq4] = make_float4(hj0.w, hj1.w, hj2.w, hj3.w);
            }
        }
        __syncthreads();   // barrier B: Hst ready
    }

    // ---- write h -> out (B, Cout, H, W) ----
    for (int k = t; k < COUT * 16; k += NTHR) {
        const int j = k >> 4;
        const int p = k & 15;
        out[((size_t)b * COUT + j) * HW_ + hw0 + p] = Hst[p][j];
    }
}

extern "C" void kernel_launch(void* const* d_in, const int* in_sizes, int n_in,
                              void* d_out, int out_size, void* d_ws, size_t ws_size,
                              hipStream_t stream) {
    const float* x  = (const float*)d_in[0];
    const float* w  = (const float*)d_in[1];
    const float* h0 = (const float*)d_in[2];
    float* out = (float*)d_out;
    nmf_kernel<<<256, NTHR, 0, stream>>>(x, w, h0, out);
}

// Round 18
// 15.756 us; speedup vs baseline: 2.2893x; 2.2893x over previous
//
#include <hip/hip_runtime.h>

#define CIN 64
#define COUT 96
#define HW_  1024
#define NTHR 512
#define NITER 5
#define NMF_EPS 1e-20f

// Round-18: MFMA engine swap. The ~28us floor (R5/R14/R16) is LDS operand
// delivery: fp32 VALU needs 1 b128 (~12cyc) per 4-8 FMAs. MFMA reads
// operands from VGPR fragments: 2 b128 per 16KFLOP. Precision via bf16
// hi/lo 3-term split (rel err ~1.6e-5). Layouts (guide §3, m89-verified D):
//   A: row=l&15, k=(l>>4)*8+e   B: col=l&15, k=(l>>4)*8+e
//   D: col=l&15, row=(l>>4)*4+reg
typedef short bf16x8 __attribute__((ext_vector_type(8)));
typedef float f32x4  __attribute__((ext_vector_type(4)));

__device__ __forceinline__ unsigned short bf_hi(float x) {       // truncate (exact residual)
    return (unsigned short)(__float_as_uint(x) >> 16);
}
__device__ __forceinline__ float bf_f(unsigned short u) {
    return __uint_as_float(((unsigned int)u) << 16);
}
__device__ __forceinline__ unsigned short bf_rn(float x) {       // round-nearest-even
    unsigned int b = __float_as_uint(x);
    b += 0x7FFF + ((b >> 16) & 1);
    return (unsigned short)(b >> 16);
}

__global__ __launch_bounds__(NTHR) void nmf_kernel(
    const float* __restrict__ x,
    const float* __restrict__ w,
    const float* __restrict__ h0,
    float* __restrict__ out)
{
    // k-major bf16 operand stores; row strides padded for bank spread, 16B-aligned
    __shared__ unsigned short Wa_hi[CIN][104],  Wa_lo[CIN][104];   // W[i][j]  (S1 A)
    __shared__ unsigned short Wt_hi[COUT][72],  Wt_lo[COUT][72];   // W^T[j][i] (S2 A)
    __shared__ unsigned short Hb_hi[16][104],   Hb_lo[16][104];    // H[j][px] as [px][j] (S1 B)
    __shared__ unsigned short Tb_hi[16][72],    Tb_lo[16][72];     // T[i][px] as [px][i] (S2 B)
    __shared__ float Par[6][16];

    const int t    = threadIdx.x;
    const int wid  = t >> 6;
    const int l    = t & 63;
    const int px   = l & 15;      // A-row / B-col / D-col lane index
    const int quad = l >> 4;      // k-group / D-row-group
    const int tile = blockIdx.x;
    const int b    = tile >> 6;
    const int hw0  = (tile & 63) << 4;

    // ---- one-time: W -> bf16 hi/lo in both orientations ----
    {
        const int i  = t >> 3;
        const int j0 = (t & 7) * 12;
        #pragma unroll
        for (int e = 0; e < 12; ++e) {
            const float v = w[i * COUT + j0 + e];
            const unsigned short hi = bf_hi(v);
            const unsigned short lo = bf_rn(v - bf_f(hi));
            Wa_hi[i][j0 + e] = hi;  Wa_lo[i][j0 + e] = lo;
            Wt_hi[j0 + e][i] = hi;  Wt_lo[j0 + e][i] = lo;
        }
    }
    // ---- one-time: H init (uniform h0) ----
    for (int k = t; k < 16 * COUT; k += NTHR) {
        const int p = k / COUT;
        const int j = k - p * COUT;
        const float v = h0[j];
        const unsigned short hi = bf_hi(v);
        Hb_hi[p][j] = hi;
        Hb_lo[p][j] = bf_rn(v - bf_f(hi));
    }

    // x at stage-1 D positions (i = wid*16+quad*4+r, col px), waves 0-3
    float xq0 = 0.f, xq1 = 0.f, xq2 = 0.f, xq3 = 0.f;
    if (wid < 4) {
        const int i0 = wid * 16 + quad * 4;
        const size_t base = ((size_t)b * CIN + i0) * HW_ + hw0 + px;
        xq0 = x[base]; xq1 = x[base + HW_]; xq2 = x[base + 2 * HW_]; xq3 = x[base + 3 * HW_];
    }
    // h fp32 in regs at stage-2 D positions (j = wid*16+quad*4+r, col px), waves 0-5
    const int j0s2 = wid * 16 + quad * 4;
    float hr0 = 0.f, hr1 = 0.f, hr2 = 0.f, hr3 = 0.f;
    if (wid < 6) {
        hr0 = h0[j0s2]; hr1 = h0[j0s2 + 1]; hr2 = h0[j0s2 + 2]; hr3 = h0[j0s2 + 3];
    }
    __syncthreads();

    #pragma unroll 1
    for (int it = 0; it < NITER; ++it) {
        // ---- stage 1 (waves 0-3): denom = W·H, 9 MFMA; t = x/(denom+eps) ----
        if (wid < 4) {
            f32x4 acc = {0.f, 0.f, 0.f, 0.f};
            #pragma unroll
            for (int ks = 0; ks < 3; ++ks) {
                const int k0 = ks * 32 + quad * 8;
                const bf16x8 ah = *(const bf16x8*)&Wa_hi[wid * 16 + px][k0];
                const bf16x8 al = *(const bf16x8*)&Wa_lo[wid * 16 + px][k0];
                const bf16x8 bh = *(const bf16x8*)&Hb_hi[px][k0];
                const bf16x8 bl = *(const bf16x8*)&Hb_lo[px][k0];
                acc = __builtin_amdgcn_mfma_f32_16x16x32_bf16(ah, bh, acc, 0, 0, 0);
                acc = __builtin_amdgcn_mfma_f32_16x16x32_bf16(al, bh, acc, 0, 0, 0);
                acc = __builtin_amdgcn_mfma_f32_16x16x32_bf16(ah, bl, acc, 0, 0, 0);
            }
            const float t0 = xq0 / (acc[0] + NMF_EPS);
            const float t1 = xq1 / (acc[1] + NMF_EPS);
            const float t2 = xq2 / (acc[2] + NMF_EPS);
            const float t3 = xq3 / (acc[3] + NMF_EPS);
            const int i0 = wid * 16 + quad * 4;
            ushort4 th, tl;
            th.x = bf_hi(t0); tl.x = bf_rn(t0 - bf_f(th.x));
            th.y = bf_hi(t1); tl.y = bf_rn(t1 - bf_f(th.y));
            th.z = bf_hi(t2); tl.z = bf_rn(t2 - bf_f(th.z));
            th.w = bf_hi(t3); tl.w = bf_rn(t3 - bf_f(th.w));
            *(ushort4*)&Tb_hi[px][i0] = th;
            *(ushort4*)&Tb_lo[px][i0] = tl;
        }
        __syncthreads();   // Tb ready

        // ---- stage 2 (waves 0-5): u = W^T·T, 6 MFMA; h' = h(1+u); row-sums ----
        float hp0 = 0.f, hp1 = 0.f, hp2 = 0.f, hp3 = 0.f;
        if (wid < 6) {
            f32x4 acc = {0.f, 0.f, 0.f, 0.f};
            #pragma unroll
            for (int ks = 0; ks < 2; ++ks) {
                const int k0 = ks * 32 + quad * 8;
                const bf16x8 ah = *(const bf16x8*)&Wt_hi[wid * 16 + px][k0];
                const bf16x8 al = *(const bf16x8*)&Wt_lo[wid * 16 + px][k0];
                const bf16x8 bh = *(const bf16x8*)&Tb_hi[px][k0];
                const bf16x8 bl = *(const bf16x8*)&Tb_lo[px][k0];
                acc = __builtin_amdgcn_mfma_f32_16x16x32_bf16(ah, bh, acc, 0, 0, 0);
                acc = __builtin_amdgcn_mfma_f32_16x16x32_bf16(al, bh, acc, 0, 0, 0);
                acc = __builtin_amdgcn_mfma_f32_16x16x32_bf16(ah, bl, acc, 0, 0, 0);
            }
            hp0 = hr0 * (1.f + acc[0]);
            hp1 = hr1 * (1.f + acc[1]);
            hp2 = hr2 * (1.f + acc[2]);
            hp3 = hr3 * (1.f + acc[3]);
            float s = (hp0 + hp1) + (hp2 + hp3);          // 4 j-rows local
            s += __shfl_xor(s, 16, 64);                   // combine quad groups
            s += __shfl_xor(s, 32, 64);
            if (l < 16) Par[wid][l] = s;                  // per-M-tile px sums
        }
        __syncthreads();   // Par ready

        if (wid < 6) {
            const float tot = NMF_EPS +
                ((Par[0][px] + Par[1][px]) + (Par[2][px] + Par[3][px])) +
                (Par[4][px] + Par[5][px]);
            const float inv = 1.f / tot;
            hr0 = hp0 * inv; hr1 = hp1 * inv; hr2 = hp2 * inv; hr3 = hp3 * inv;
            if (it < NITER - 1) {                          // bf16-split h for next iter
                ushort4 hh, hl;
                hh.x = bf_hi(hr0); hl.x = bf_rn(hr0 - bf_f(hh.x));
                hh.y = bf_hi(hr1); hl.y = bf_rn(hr1 - bf_f(hh.y));
                hh.z = bf_hi(hr2); hl.z = bf_rn(hr2 - bf_f(hh.z));
                hh.w = bf_hi(hr3); hl.w = bf_rn(hr3 - bf_f(hh.w));
                *(ushort4*)&Hb_hi[px][j0s2] = hh;
                *(ushort4*)&Hb_lo[px][j0s2] = hl;
            }
        }
        __syncthreads();   // Hb ready
    }

    // ---- write h (fp32 regs) -> out (B, Cout, H, W) ----
    if (wid < 6) {
        const size_t base = ((size_t)b * COUT + j0s2) * HW_ + hw0 + px;
        out[base]           = hr0;
        out[base + HW_]     = hr1;
        out[base + 2 * HW_] = hr2;
        out[base + 3 * HW_] = hr3;
    }
}

extern "C" void kernel_launch(void* const* d_in, const int* in_sizes, int n_in,
                              void* d_out, int out_size, void* d_ws, size_t ws_size,
                              hipStream_t stream) {
    const float* x  = (const float*)d_in[0];
    const float* w  = (const float*)d_in[1];
    const float* h0 = (const float*)d_in[2];
    float* out = (float*)d_out;
    nmf_kernel<<<256, NTHR, 0, stream>>>(x, w, h0, out);
}

// Round 21
// 12.376 us; speedup vs baseline: 2.9145x; 1.2731x over previous
//
#include <hip/hip_runtime.h>

#define CIN 64
#define COUT 96
#define HW_  1024
#define NTHR 512
#define NITER 5
#define NMF_EPS 1e-20f

// Round-19: W fragments hoisted to registers (loaded once from GLOBAL, no LDS
// W buffers). Per-iter LDS traffic = B operands only (Hb, Tb). bf16 hi/lo
// 3-term MFMA emulation as R18 (absmax 1.2e-4 proven). rcp instead of div.
typedef short bf16x8 __attribute__((ext_vector_type(8)));
typedef float f32x4  __attribute__((ext_vector_type(4)));

__device__ __forceinline__ unsigned short bf_hi(float x) {
    return (unsigned short)(__float_as_uint(x) >> 16);
}
__device__ __forceinline__ float bf_f(unsigned short u) {
    return __uint_as_float(((unsigned int)u) << 16);
}
__device__ __forceinline__ unsigned short bf_rn(float x) {
    unsigned int b = __float_as_uint(x);
    b += 0x7FFF + ((b >> 16) & 1);
    return (unsigned short)(b >> 16);
}
__device__ __forceinline__ void split8(const float* v, bf16x8& hi, bf16x8& lo) {
    #pragma unroll
    for (int e = 0; e < 8; ++e) {
        const unsigned short h = bf_hi(v[e]);
        hi[e] = (short)h;
        lo[e] = (short)bf_rn(v[e] - bf_f(h));
    }
}

__global__ __launch_bounds__(NTHR) void nmf_kernel(
    const float* __restrict__ x,
    const float* __restrict__ w,
    const float* __restrict__ h0,
    float* __restrict__ out)
{
    __shared__ unsigned short Hb_hi[16][104], Hb_lo[16][104];  // H as [px][j]
    __shared__ unsigned short Tb_hi[16][72],  Tb_lo[16][72];   // T as [px][i]
    __shared__ float Par[6][16];

    const int t    = threadIdx.x;
    const int wid  = t >> 6;
    const int l    = t & 63;
    const int px   = l & 15;
    const int quad = l >> 4;
    const int tile = blockIdx.x;
    const int b    = tile >> 6;
    const int hw0  = (tile & 63) << 4;

    // ---- one-time: H init (uniform h0) ----
    for (int k = t; k < 16 * COUT; k += NTHR) {
        const int p = k / COUT;
        const int j = k - p * COUT;
        const float v = h0[j];
        const unsigned short hi = bf_hi(v);
        Hb_hi[p][j] = hi;
        Hb_lo[p][j] = bf_rn(v - bf_f(hi));
    }

    // ---- one-time: S1 A-frags from global: W[i=wid*16+px][j=ks*32+quad*8+e] ----
    bf16x8 a1h0, a1l0, a1h1, a1l1, a1h2, a1l2;
    if (wid < 4) {
        const float* wrow = &w[(wid * 16 + px) * COUT + quad * 8];
        float v[8];
        #pragma unroll
        for (int e = 0; e < 8; ++e) v[e] = wrow[e];
        split8(v, a1h0, a1l0);
        #pragma unroll
        for (int e = 0; e < 8; ++e) v[e] = wrow[32 + e];
        split8(v, a1h1, a1l1);
        #pragma unroll
        for (int e = 0; e < 8; ++e) v[e] = wrow[64 + e];
        split8(v, a1h2, a1l2);
    }
    // ---- one-time: S2 A-frags: W^T[j=wid*16+px][i=ks*32+quad*8+e] (strided) ----
    bf16x8 a2h0, a2l0, a2h1, a2l1;
    const int j0s2 = wid * 16 + quad * 4;      // S2 D rows (j), also used for out
    if (wid < 6) {
        const int jcol = wid * 16 + px;
        float v[8];
        #pragma unroll
        for (int e = 0; e < 8; ++e) v[e] = w[(quad * 8 + e) * COUT + jcol];
        split8(v, a2h0, a2l0);
        #pragma unroll
        for (int e = 0; e < 8; ++e) v[e] = w[(32 + quad * 8 + e) * COUT + jcol];
        split8(v, a2h1, a2l1);
    }

    // x at S1 D positions (rows i = wid*16+quad*4.., col px)
    float xq0 = 0.f, xq1 = 0.f, xq2 = 0.f, xq3 = 0.f;
    if (wid < 4) {
        const size_t base = ((size_t)b * CIN + wid * 16 + quad * 4) * HW_ + hw0 + px;
        xq0 = x[base]; xq1 = x[base + HW_]; xq2 = x[base + 2 * HW_]; xq3 = x[base + 3 * HW_];
    }
    // h fp32 in regs at S2 D positions (rows j = j0s2.., col px)
    float hr0 = 0.f, hr1 = 0.f, hr2 = 0.f, hr3 = 0.f;
    if (wid < 6) {
        hr0 = h0[j0s2]; hr1 = h0[j0s2 + 1]; hr2 = h0[j0s2 + 2]; hr3 = h0[j0s2 + 3];
    }
    __syncthreads();

    #pragma unroll 1
    for (int it = 0; it < NITER; ++it) {
        // ---- stage 1 (waves 0-3): denom = W·H (9 MFMA); t = x*rcp(denom+eps) ----
        if (wid < 4) {
            f32x4 acc = {0.f, 0.f, 0.f, 0.f};
            {
                const bf16x8 bh = *(const bf16x8*)&Hb_hi[px][quad * 8];
                const bf16x8 bl = *(const bf16x8*)&Hb_lo[px][quad * 8];
                acc = __builtin_amdgcn_mfma_f32_16x16x32_bf16(a1h0, bh, acc, 0, 0, 0);
                acc = __builtin_amdgcn_mfma_f32_16x16x32_bf16(a1l0, bh, acc, 0, 0, 0);
                acc = __builtin_amdgcn_mfma_f32_16x16x32_bf16(a1h0, bl, acc, 0, 0, 0);
            }
            {
                const bf16x8 bh = *(const bf16x8*)&Hb_hi[px][32 + quad * 8];
                const bf16x8 bl = *(const bf16x8*)&Hb_lo[px][32 + quad * 8];
                acc = __builtin_amdgcn_mfma_f32_16x16x32_bf16(a1h1, bh, acc, 0, 0, 0);
                acc = __builtin_amdgcn_mfma_f32_16x16x32_bf16(a1l1, bh, acc, 0, 0, 0);
                acc = __builtin_amdgcn_mfma_f32_16x16x32_bf16(a1h1, bl, acc, 0, 0, 0);
            }
            {
                const bf16x8 bh = *(const bf16x8*)&Hb_hi[px][64 + quad * 8];
                const bf16x8 bl = *(const bf16x8*)&Hb_lo[px][64 + quad * 8];
                acc = __builtin_amdgcn_mfma_f32_16x16x32_bf16(a1h2, bh, acc, 0, 0, 0);
                acc = __builtin_amdgcn_mfma_f32_16x16x32_bf16(a1l2, bh, acc, 0, 0, 0);
                acc = __builtin_amdgcn_mfma_f32_16x16x32_bf16(a1h2, bl, acc, 0, 0, 0);
            }
            const float t0 = xq0 * __builtin_amdgcn_rcpf(acc[0] + NMF_EPS);
            const float t1 = xq1 * __builtin_amdgcn_rcpf(acc[1] + NMF_EPS);
            const float t2 = xq2 * __builtin_amdgcn_rcpf(acc[2] + NMF_EPS);
            const float t3 = xq3 * __builtin_amdgcn_rcpf(acc[3] + NMF_EPS);
            const int i0 = wid * 16 + quad * 4;
            ushort4 th, tl;
            th.x = bf_hi(t0); tl.x = bf_rn(t0 - bf_f(th.x));
            th.y = bf_hi(t1); tl.y = bf_rn(t1 - bf_f(th.y));
            th.z = bf_hi(t2); tl.z = bf_rn(t2 - bf_f(th.z));
            th.w = bf_hi(t3); tl.w = bf_rn(t3 - bf_f(th.w));
            *(ushort4*)&Tb_hi[px][i0] = th;
            *(ushort4*)&Tb_lo[px][i0] = tl;
        }
        __syncthreads();   // Tb ready

        // ---- stage 2 (waves 0-5): u = W^T·T (6 MFMA); h' = h(1+u); row sums ----
        float hp0 = 0.f, hp1 = 0.f, hp2 = 0.f, hp3 = 0.f;
        if (wid < 6) {
            f32x4 acc = {0.f, 0.f, 0.f, 0.f};
            {
                const bf16x8 bh = *(const bf16x8*)&Tb_hi[px][quad * 8];
                const bf16x8 bl = *(const bf16x8*)&Tb_lo[px][quad * 8];
                acc = __builtin_amdgcn_mfma_f32_16x16x32_bf16(a2h0, bh, acc, 0, 0, 0);
                acc = __builtin_amdgcn_mfma_f32_16x16x32_bf16(a2l0, bh, acc, 0, 0, 0);
                acc = __builtin_amdgcn_mfma_f32_16x16x32_bf16(a2h0, bl, acc, 0, 0, 0);
            }
            {
                const bf16x8 bh = *(const bf16x8*)&Tb_hi[px][32 + quad * 8];
                const bf16x8 bl = *(const bf16x8*)&Tb_lo[px][32 + quad * 8];
                acc = __builtin_amdgcn_mfma_f32_16x16x32_bf16(a2h1, bh, acc, 0, 0, 0);
                acc = __builtin_amdgcn_mfma_f32_16x16x32_bf16(a2l1, bh, acc, 0, 0, 0);
                acc = __builtin_amdgcn_mfma_f32_16x16x32_bf16(a2h1, bl, acc, 0, 0, 0);
            }
            hp0 = hr0 * (1.f + acc[0]);
            hp1 = hr1 * (1.f + acc[1]);
            hp2 = hr2 * (1.f + acc[2]);
            hp3 = hr3 * (1.f + acc[3]);
            float s = (hp0 + hp1) + (hp2 + hp3);
            s += __shfl_xor(s, 16, 64);
            s += __shfl_xor(s, 32, 64);
            if (l < 16) Par[wid][l] = s;
        }
        __syncthreads();   // Par ready

        if (wid < 6) {
            const float tot = NMF_EPS +
                ((Par[0][px] + Par[1][px]) + (Par[2][px] + Par[3][px])) +
                (Par[4][px] + Par[5][px]);
            const float inv = __builtin_amdgcn_rcpf(tot);
            hr0 = hp0 * inv; hr1 = hp1 * inv; hr2 = hp2 * inv; hr3 = hp3 * inv;
            if (it < NITER - 1) {
                ushort4 hh, hl;
                hh.x = bf_hi(hr0); hl.x = bf_rn(hr0 - bf_f(hh.x));
                hh.y = bf_hi(hr1); hl.y = bf_rn(hr1 - bf_f(hh.y));
                hh.z = bf_hi(hr2); hl.z = bf_rn(hr2 - bf_f(hh.z));
                hh.w = bf_hi(hr3); hl.w = bf_rn(hr3 - bf_f(hh.w));
                *(ushort4*)&Hb_hi[px][j0s2] = hh;
                *(ushort4*)&Hb_lo[px][j0s2] = hl;
            }
        }
        __syncthreads();   // Hb ready
    }

    // ---- write h (fp32 regs) -> out (B, Cout, H, W) ----
    if (wid < 6) {
        const size_t base = ((size_t)b * COUT + j0s2) * HW_ + hw0 + px;
        out[base]           = hr0;
        out[base + HW_]     = hr1;
        out[base + 2 * HW_] = hr2;
        out[base + 3 * HW_] = hr3;
    }
}

extern "C" void kernel_launch(void* const* d_in, const int* in_sizes, int n_in,
                              void* d_out, int out_size, void* d_ws, size_t ws_size,
                              hipStream_t stream) {
    const float* x  = (const float*)d_in[0];
    const float* w  = (const float*)d_in[1];
    const float* h0 = (const float*)d_in[2];
    float* out = (float*)d_out;
    nmf_kernel<<<256, NTHR, 0, stream>>>(x, w, h0, out);
}